// Round 5
// baseline (592.120 us; speedup 1.0000x reference)
//
#include <hip/hip_runtime.h>
#include <hip/hip_bf16.h>
#include <cstdint>
#include <cstddef>

#define N_NODES 100000
#define DIM 512
#define NE 200000
#define NSB 196    // ceil(N_NODES/512)

typedef __attribute__((ext_vector_type(4))) float floatx4;
typedef __attribute__((ext_vector_type(8))) short shortx8;
typedef __attribute__((ext_vector_type(4))) short shortx4;

__device__ __forceinline__ unsigned short f2bf(float f) {
    union { float f; uint32_t u; } v; v.f = f;
    uint32_t r = v.u + 0x7fff + ((v.u >> 16) & 1);   // RNE
    return (unsigned short)(r >> 16);
}

__device__ __forceinline__ float bf2f(unsigned short h) {
    union { uint32_t u; float f; } v; v.u = ((uint32_t)h) << 16;
    return v.f;
}

// 8x fp32 -> 8x bf16 (RNE) via packed v_cvt_pk_bf16_f32
__device__ __forceinline__ shortx8 cvt8(const float4 a, const float4 b) {
    union { __hip_bfloat162 h2[4]; shortx8 s8; } u;
    u.h2[0] = __float22bfloat162_rn(make_float2(a.x, a.y));
    u.h2[1] = __float22bfloat162_rn(make_float2(a.z, a.w));
    u.h2[2] = __float22bfloat162_rn(make_float2(b.x, b.y));
    u.h2[3] = __float22bfloat162_rn(make_float2(b.z, b.w));
    return u.s8;
}

__device__ __forceinline__ void load_lds16(const void* g, void* l) {
    __builtin_amdgcn_global_load_lds(
        (const __attribute__((address_space(1))) uint32_t*)g,
        (__attribute__((address_space(3))) uint32_t*)l, 16, 0, 0);
}

// ---------------- per-etype in-degree counts + Wc = (W0+W1+W2)/3 (fused, independent) ----
__global__ __launch_bounds__(256) void count_combine_kernel(
    const int* __restrict__ d0, const int* __restrict__ d1,
    const int* __restrict__ d2, int* __restrict__ cnt,
    const float* __restrict__ W0, const float* __restrict__ W1,
    const float* __restrict__ W2, unsigned short* __restrict__ Wc) {
    int t = blockIdx.x * 256 + threadIdx.x;
    if (t < DIM * DIM)
        Wc[t] = f2bf((W0[t] + W1[t] + W2[t]) * (1.0f / 3.0f));
    if (t < 3 * NE) {
        int e = t / NE;
        int i = t - e * NE;
        const int* dp = (e == 0) ? d0 : (e == 1) ? d1 : d2;
        atomicAdd(&cnt[e * N_NODES + dp[i]], 1);
    }
}

// ---------------- scan pass 1: per-block (512 rows) sums of total row length ----------------
__global__ __launch_bounds__(512) void scan1_kernel(
    const int* __restrict__ cnt, int* __restrict__ bsum) {
    int t = threadIdx.x;
    int n = blockIdx.x * 512 + t;
    int rl = 0;
    if (n < N_NODES) rl = cnt[n] + cnt[N_NODES + n] + cnt[2 * N_NODES + n];
    int v = rl;
    #pragma unroll
    for (int off = 32; off > 0; off >>= 1) v += __shfl_xor(v, off);
    __shared__ int ws_[8];
    if ((t & 63) == 0) ws_[t >> 6] = v;
    __syncthreads();
    if (t == 0) {
        int s = 0;
        #pragma unroll
        for (int i = 0; i < 8; ++i) s += ws_[i];
        bsum[blockIdx.x] = s;
    }
}

// ---------------- scan pass 2+3 fused: each block scans the 196 block sums in LDS,
// then scans its own 512 row lengths -> row_start + cursor ----------------
__global__ __launch_bounds__(512) void scan3_kernel(
    const int* __restrict__ cnt, const int* __restrict__ bsum,
    int* __restrict__ row_start, int* __restrict__ cursor) {
    __shared__ int shb[512];
    __shared__ int sh[512];
    int t = threadIdx.x;
    // inclusive scan of block sums (196 valid, padded 0)
    shb[t] = (t < NSB) ? bsum[t] : 0;
    __syncthreads();
    #pragma unroll
    for (int off = 1; off < 512; off <<= 1) {
        int add = (t >= off) ? shb[t - off] : 0;
        __syncthreads();
        shb[t] += add;
        __syncthreads();
    }
    // this block's row lengths
    int n = blockIdx.x * 512 + t;
    int rl = 0;
    if (n < N_NODES) rl = cnt[n] + cnt[N_NODES + n] + cnt[2 * N_NODES + n];
    sh[t] = rl;
    __syncthreads();
    #pragma unroll
    for (int off = 1; off < 512; off <<= 1) {
        int add = (t >= off) ? sh[t - off] : 0;
        __syncthreads();
        sh[t] += add;
        __syncthreads();
    }
    if (n < N_NODES) {
        int bexcl = shb[blockIdx.x] - bsum[blockIdx.x];   // exclusive block prefix
        int excl = sh[t] - rl + bexcl;
        row_start[n] = excl;
        cursor[n] = excl;
    }
}

// ---------------- bin edges into CSR: src tagged with etype in bits 30-31 ----------------
__global__ __launch_bounds__(256) void bin_kernel(
    const int* __restrict__ s0, const int* __restrict__ d0,
    const int* __restrict__ s1, const int* __restrict__ d1,
    const int* __restrict__ s2, const int* __restrict__ d2,
    int* __restrict__ cursor, int* __restrict__ src_tag) {
    int t = blockIdx.x * 256 + threadIdx.x;
    if (t >= 3 * NE) return;
    int e = t / NE;
    int i = t - e * NE;
    const int* sp; const int* dp;
    if (e == 0)      { sp = s0; dp = d0; }
    else if (e == 1) { sp = s1; dp = d1; }
    else             { sp = s2; dp = d2; }
    int d = dp[i];
    int pos = atomicAdd(&cursor[d], 1);
    src_tag[pos] = sp[i] | (e << 30);
}

// ---------------- GEMM: H = bf16(X) @ Wc^T, double-buffered 2-phase ----------------
// 128x128 tile, BK=64 (8 K-tiles), 256 threads = 2x2 waves, 4x4 16x16x32 frags/wave.
// LDS: row-major [128][64] bf16, 16B-octet XOR swizzle (c ^ row&7); round-4 verified.
// 2-phase schedule (catalog T3 minimum): stage tile t+1 into buf^1 BEFORE computing
// tile t, so the vmcnt(0) drain at the single end-of-step barrier is covered by the
// 16 ds_read + 32 MFMA of tile t (round-4 issued B right before the drain -> full
// latency exposed -> MfmaUtil 16.9%). A: fp32 global -> 2-deep reg pipeline (tile t+1
// loaded 2 iters ahead, ~2 compute phases of HBM cover) -> cvt_pk -> swizzled ds_write.
// B: global_load_lds, linear dest + octet-permuted per-lane global source.
// Loop fully unrolled so all buffer/parity indices are compile-time (no scratch).
// XCD-bijective swizzle: 3128 = 8*391 blocks; 4 N-tile siblings share one XCD's L2.
__global__ __launch_bounds__(256) void gemm_kernel(
    const float* __restrict__ X, const unsigned short* __restrict__ B,
    unsigned short* __restrict__ H, int M) {
    __shared__ alignas(16) unsigned short As[2][128 * 64];   // 2 x 16 KB
    __shared__ alignas(16) unsigned short Bs[2][128 * 64];   // 2 x 16 KB
    const int tid = threadIdx.x;
    const int lane = tid & 63;
    const int w = tid >> 6;            // 0..3
    const int wr = w >> 1, wc = w & 1; // wave grid 2x2
    const int q = lane >> 4, r = lane & 15;

    int lid = ((int)blockIdx.x & 7) * 391 + ((int)blockIdx.x >> 3);
    int mt = lid >> 2, nt = lid & 3;
    int m0 = mt * 128, n0 = nt * 128;

    // A staging geometry: chunk ca = i*256 + tid; row = i*32 + (tid>>3), octet = tid&7
    const int arow = tid >> 3;          // 0..31
    const int ac = tid & 7;             // k-octet
    const int acs = ac ^ (arow & 7);    // swizzled octet position
    const unsigned abyte = (unsigned)arow * 128 + (unsigned)acs * 16;
    const float* aptr[4];
    #pragma unroll
    for (int i = 0; i < 4; ++i) {
        int gm = m0 + i * 32 + arow; if (gm >= M) gm = M - 1;   // clamp tail reads
        aptr[i] = X + (size_t)gm * DIM + ac * 8;
    }

    float4 areg[2][4][2];   // 2-deep pipeline, parity p = tile index & 1
    auto aload = [&](int p, int k0_) {
        #pragma unroll
        for (int i = 0; i < 4; ++i) {
            areg[p][i][0] = *(const float4*)(aptr[i] + k0_);
            areg[p][i][1] = *(const float4*)(aptr[i] + k0_ + 4);
        }
    };
    auto writeA = [&](int buf, int p) {
        #pragma unroll
        for (int i = 0; i < 4; ++i)
            *(shortx8*)((char*)As[buf] + i * 4096 + abyte) =
                cvt8(areg[p][i][0], areg[p][i][1]);
    };
    auto stageB = [&](int buf, int k0_) {
        #pragma unroll
        for (int i = 0; i < 4; ++i) {
            int ch = i * 256 + tid;
            int row = ch >> 3, c0_ = ch & 7;
            int cs = c0_ ^ (row & 7);
            load_lds16(&B[(size_t)(n0 + row) * DIM + k0_ + cs * 8], &Bs[buf][ch * 8]);
        }
    };

    floatx4 acc[4][4] = {};

    // prologue: tile0 -> LDS buf0; tiles 1,2 -> regs
    aload(0, 0);          // tile 0 (parity 0)
    stageB(0, 0);
    writeA(0, 0);         // consumes tile 0
    aload(1, 64);         // tile 1 (parity 1)
    aload(0, 128);        // tile 2 (parity 0)
    __syncthreads();

    #pragma unroll
    for (int t = 0; t < 8; ++t) {
        const int cur = t & 1;
        if (t < 7) {
            stageB(cur ^ 1, (t + 1) * 64);        // B tile t+1 -> other buffer
            writeA(cur ^ 1, (t + 1) & 1);         // A tile t+1 (regs loaded iter t-1)
            if (t < 5) aload((t + 1) & 1, (t + 3) * 64);   // refill: tile t+3
        }
        #pragma unroll
        for (int kk = 0; kk < 2; ++kk) {
            const int kq = kk * 4 + q;                 // k-octet 0..7
            const int sc = (kq ^ (r & 7)) * 16;        // swizzled byte-in-row
            shortx8 af[4], bfr[4];
            #pragma unroll
            for (int mi = 0; mi < 4; ++mi)
                af[mi] = *(const shortx8*)((const char*)As[cur] +
                         (wr * 64 + mi * 16 + r) * 128 + sc);
            #pragma unroll
            for (int nj = 0; nj < 4; ++nj)
                bfr[nj] = *(const shortx8*)((const char*)Bs[cur] +
                          (wc * 64 + nj * 16 + r) * 128 + sc);
            #pragma unroll
            for (int mi = 0; mi < 4; ++mi)
                #pragma unroll
                for (int nj = 0; nj < 4; ++nj)
                    acc[mi][nj] = __builtin_amdgcn_mfma_f32_16x16x32_bf16(
                        af[mi], bfr[nj], acc[mi][nj], 0, 0, 0);
        }
        __syncthreads();   // drains next-tile staging (covered by the MFMAs above)
    }

    // C/D layout: col = r, row = q*4 + rg within each 16x16 frag
    #pragma unroll
    for (int mi = 0; mi < 4; ++mi) {
        #pragma unroll
        for (int rg = 0; rg < 4; ++rg) {
            int gm = m0 + wr * 64 + mi * 16 + q * 4 + rg;
            if (gm < M) {
                #pragma unroll
                for (int nj = 0; nj < 4; ++nj)
                    H[(size_t)gm * DIM + n0 + wc * 64 + nj * 16 + r] =
                        f2bf(acc[mi][nj][rg]);
            }
        }
    }
}

// ---------------- fused gather + ReLU + LayerNorm (2 waves per node) ----------------
// Block = 256 threads = 2 nodes x 2 waves; each wave owns a 256-dim half (4 elems/lane).
// Halved per-wave chain + doubled independent load streams vs 1-wave/node. LN stats
// combined across the wave pair via LDS. Cooperative tag load + 4-wide MLP unroll.
__global__ __launch_bounds__(256) void gather_ln_kernel(
    const unsigned short* __restrict__ h, const int* __restrict__ row_start,
    const int* __restrict__ cnt, const int* __restrict__ src_tag,
    const float* __restrict__ gamma, const float* __restrict__ beta,
    float* __restrict__ out) {
    const int tid = threadIdx.x;
    const int lane = tid & 63;
    const int half = (tid >> 6) & 1;
    const int nloc = tid >> 7;               // 0..1
    const int n = blockIdx.x * 2 + nloc;
    __shared__ float red[2][2][2];           // [node][half][s1,s2]
    const bool alive = (n < N_NODES);

    int len = 0, beg = 0;
    float w0 = 0.0f, w1 = 0.0f, w2 = 0.0f;
    if (alive) {
        int c0 = cnt[n], c1 = cnt[N_NODES + n], c2 = cnt[2 * N_NODES + n];
        len = c0 + c1 + c2;
        w0 = 1.0f / (3.0f * (float)max(c0, 1));
        w1 = 1.0f / (3.0f * (float)max(c1, 1));
        w2 = 1.0f / (3.0f * (float)max(c2, 1));
        beg = row_start[n];
    }
    const int d0 = half * 256 + lane * 4;    // my 4 dims
    float acc[4] = {};
    if (alive) {
        for (int base = 0; base < len; base += 64) {
            int rem = len - base;
            int m = rem < 64 ? rem : 64;
            int tag = (lane < m) ? src_tag[beg + base + lane] : 0;
            int j = 0;
            for (; j + 4 <= m; j += 4) {
                int u0 = __shfl(tag, j),     u1 = __shfl(tag, j + 1);
                int u2 = __shfl(tag, j + 2), u3 = __shfl(tag, j + 3);
                float g0 = (((unsigned)u0 >> 30) == 0) ? w0 : ((((unsigned)u0 >> 30) == 1) ? w1 : w2);
                float g1 = (((unsigned)u1 >> 30) == 0) ? w0 : ((((unsigned)u1 >> 30) == 1) ? w1 : w2);
                float g2 = (((unsigned)u2 >> 30) == 0) ? w0 : ((((unsigned)u2 >> 30) == 1) ? w1 : w2);
                float g3 = (((unsigned)u3 >> 30) == 0) ? w0 : ((((unsigned)u3 >> 30) == 1) ? w1 : w2);
                shortx4 v0 = *(const shortx4*)(h + (size_t)(u0 & 0x3FFFFFFF) * DIM + d0);
                shortx4 v1 = *(const shortx4*)(h + (size_t)(u1 & 0x3FFFFFFF) * DIM + d0);
                shortx4 v2 = *(const shortx4*)(h + (size_t)(u2 & 0x3FFFFFFF) * DIM + d0);
                shortx4 v3 = *(const shortx4*)(h + (size_t)(u3 & 0x3FFFFFFF) * DIM + d0);
                #pragma unroll
                for (int k = 0; k < 4; ++k) {
                    acc[k] += bf2f((unsigned short)v0[k]) * g0;
                    acc[k] += bf2f((unsigned short)v1[k]) * g1;
                    acc[k] += bf2f((unsigned short)v2[k]) * g2;
                    acc[k] += bf2f((unsigned short)v3[k]) * g3;
                }
            }
            for (; j < m; ++j) {
                int u = __shfl(tag, j);
                float wg = (((unsigned)u >> 30) == 0) ? w0 : ((((unsigned)u >> 30) == 1) ? w1 : w2);
                shortx4 v = *(const shortx4*)(h + (size_t)(u & 0x3FFFFFFF) * DIM + d0);
                #pragma unroll
                for (int k = 0; k < 4; ++k)
                    acc[k] += bf2f((unsigned short)v[k]) * wg;
            }
        }
    }
    // ReLU + partial stats over this wave's 256 dims
    float s1 = 0.0f, s2 = 0.0f;
    #pragma unroll
    for (int k = 0; k < 4; ++k) {
        float v = fmaxf(acc[k], 0.0f);
        acc[k] = v; s1 += v; s2 += v * v;
    }
    #pragma unroll
    for (int off = 1; off < 64; off <<= 1) {
        s1 += __shfl_xor(s1, off);
        s2 += __shfl_xor(s2, off);
    }
    if (lane == 0) { red[nloc][half][0] = s1; red[nloc][half][1] = s2; }
    __syncthreads();
    float S1 = red[nloc][0][0] + red[nloc][1][0];
    float S2 = red[nloc][0][1] + red[nloc][1][1];
    if (alive) {
        float mu = S1 * (1.0f / DIM);
        float var = S2 * (1.0f / DIM) - mu * mu;
        float rstd = rsqrtf(var + 1e-5f);
        float4 g = *(const float4*)(gamma + d0);
        float4 b = *(const float4*)(beta + d0);
        float4 o;
        o.x = (acc[0] - mu) * rstd * g.x + b.x;
        o.y = (acc[1] - mu) * rstd * g.y + b.y;
        o.z = (acc[2] - mu) * rstd * g.z + b.z;
        o.w = (acc[3] - mu) * rstd * g.w + b.w;
        *(float4*)(out + (size_t)n * DIM + d0) = o;
    }
}

extern "C" void kernel_launch(void* const* d_in, const int* in_sizes, int n_in,
                              void* d_out, int out_size, void* d_ws, size_t ws_size,
                              hipStream_t stream) {
    const float* x     = (const float*)d_in[0];
    const float* W0    = (const float*)d_in[1];
    const float* W1    = (const float*)d_in[2];
    const float* W2    = (const float*)d_in[3];
    const float* gamma = (const float*)d_in[4];
    const float* beta  = (const float*)d_in[5];
    const int* s0  = (const int*)d_in[6];
    const int* dd0 = (const int*)d_in[7];
    const int* s1  = (const int*)d_in[8];
    const int* dd1 = (const int*)d_in[9];
    const int* s2  = (const int*)d_in[10];
    const int* dd2 = (const int*)d_in[11];
    float* out = (float*)d_out;

    // workspace layout (16B-aligned pieces)
    char* ws = (char*)d_ws;
    size_t off = 0;
    int* cnt = (int*)(ws + off);             off += 3u * N_NODES * 4u;          // 1.2 MB
    int* row_start = (int*)(ws + off);       off += (size_t)N_NODES * 4u;
    int* cursor = (int*)(ws + off);          off += (size_t)N_NODES * 4u;
    int* bsum = (int*)(ws + off);            off += 2048;
    int* src_tag = (int*)(ws + off);         off += (size_t)3 * NE * 4u;        // 2.4 MB
    unsigned short* Wc = (unsigned short*)(ws + off); off += (size_t)DIM * DIM * 2u;
    off = (off + 255) & ~255ull;
    unsigned short* h = (unsigned short*)(ws + off);                            // 102.4 MB

    hipMemsetAsync(cnt, 0, (size_t)3 * N_NODES * sizeof(int), stream);

    count_combine_kernel<<<(3 * NE + 255) / 256, 256, 0, stream>>>(
        dd0, dd1, dd2, cnt, W0, W1, W2, Wc);
    scan1_kernel<<<NSB, 512, 0, stream>>>(cnt, bsum);
    scan3_kernel<<<NSB, 512, 0, stream>>>(cnt, bsum, row_start, cursor);
    bin_kernel<<<(3 * NE + 255) / 256, 256, 0, stream>>>(
        s0, dd0, s1, dd1, s2, dd2, cursor, src_tag);

    // GEMM with fused fp32->bf16 convert on A: h = bf16(x) @ Wc^T (bf16 out).
    gemm_kernel<<<3128, 256, 0, stream>>>(x, Wc, h, N_NODES);

    // Fused aggregate + ReLU + LayerNorm (fp32 accumulate, 2 waves per node).
    gather_ln_kernel<<<(N_NODES + 1) / 2, 256, 0, stream>>>(
        h, row_start, cnt, src_tag, gamma, beta, out);
}